// Round 10
// baseline (86.727 us; speedup 1.0000x reference)
//
#include <hip/hip_runtime.h>

#define S_   96
#define B_   16
#define D_   512
#define HID_ 128
#define M_   (S_ * B_)     // 1536
#define KC_  4             // K-split chunks
#define KCH_ (D_ / KC_)    // 128 per chunk
#define CHF_ (2 * M_ * HID_)   // floats per chunk buffer (ha+hb)
#define LSTR_ 136          // LDS row stride in halfwords (272 B): uniform bank quads

// Own POD vector types only — no HIP vector classes (non-POD, poison unions).
typedef __attribute__((ext_vector_type(4))) float        f32x4_t;
typedef __attribute__((ext_vector_type(2))) float        f32x2_t;
typedef __attribute__((ext_vector_type(4))) unsigned int u32x4_t;
typedef __attribute__((ext_vector_type(8))) short        short8;   // bf16x8 MFMA frag

// Packed-FP32 (VOP3P, gfx90a+/gfx950 FeaturePackedFP32Ops). No v_pk_max_f32
// exists for f32 — ReLU stays scalar.
static __device__ __forceinline__ f32x2_t pk_add(f32x2_t a, f32x2_t b) {
    f32x2_t d;
    asm("v_pk_add_f32 %0, %1, %2" : "=v"(d) : "v"(a), "v"(b));
    return d;
}
static __device__ __forceinline__ void pk_fma(f32x2_t& acc, f32x2_t a, f32x2_t b) {
    asm("v_pk_fma_f32 %0, %1, %2, %0" : "+v"(acc) : "v"(a), "v"(b));
}

// Split 8 f32 into hi/lo truncated-bf16 fragments (3-MFMA f32-grade emulation).
static __device__ __forceinline__ void split8(f32x4_t a, f32x4_t b,
                                              short8& hi, short8& lo) {
    float f[8];
    #pragma unroll
    for (int j = 0; j < 4; ++j) { f[j] = a[j]; f[4 + j] = b[j]; }
    unsigned int hb[8], lb[8];
    #pragma unroll
    for (int j = 0; j < 8; ++j) {
        unsigned int u = __float_as_uint(f[j]);
        float hf = __uint_as_float(u & 0xffff0000u);
        hb[j] = u >> 16;
        lb[j] = __float_as_uint(f[j] - hf) >> 16;
    }
    union { u32x4_t u; short8 s; } H, L;
    #pragma unroll
    for (int j = 0; j < 4; ++j) {
        H.u[j] = hb[2 * j] | (hb[2 * j + 1] << 16);
        L.u[j] = lb[2 * j] | (lb[2 * j + 1] << 16);
    }
    hi = H.s; lo = L.s;
}

// Stage 1 (MFMA, pre-split hi/lo bf16 LDS tiles, K-split x4):
//   ws[kc][z][m][h] = sum_{d in chunk kc} x[m][d]*W1[h][z*512+d]  (+b1 at kc=0,z=0)
// grid (48 m-blocks, 2 h-halves, 4 kc), block 256 = 4 waves (2x2), wave = 32x32 C.
__global__ __launch_bounds__(256) void stage1_mfma(
    const float* __restrict__ emb,
    const float* __restrict__ embc,
    const float* __restrict__ W1,
    const float* __restrict__ b1,
    float* __restrict__ ws)
{
    __shared__ short x_hi[64 * LSTR_];
    __shared__ short x_lo[64 * LSTR_];
    __shared__ short w_hi[64 * LSTR_];
    __shared__ short w_lo[64 * LSTR_];

    const int t    = threadIdx.x;
    const int wave = t >> 6;
    const int lane = t & 63;
    const int bx   = blockIdx.x;          // m-block (64 rows); z boundary at bx=24
    const int h0   = blockIdx.y * 64;     // h-half
    const int kc   = blockIdx.z;          // k-chunk

    const int z    = (bx >= 24) ? 1 : 0;
    const int mloc = bx * 64 - z * M_;    // local row start in emb/embc

    const float* xbase = (z ? embc : emb) + (size_t)mloc * D_ + kc * KCH_;
    const float* wbase = W1 + (size_t)h0 * (2 * D_) + z * D_ + kc * KCH_;

    // Staging + one-time split: 1024 k-groups per tile, 4 per thread per tile.
    #pragma unroll
    for (int rep = 0; rep < 4; ++rep) {
        const int idx = rep * 256 + t;    // [0,1024)
        const int row = idx >> 4;         // 0..63
        const int g   = idx & 15;         // k-group 0..15 (8 floats)
        short8 hi, lo;
        const float* px = xbase + row * D_ + g * 8;
        split8(*(const f32x4_t*)px, *(const f32x4_t*)(px + 4), hi, lo);
        *(short8*)&x_hi[row * LSTR_ + g * 8] = hi;
        *(short8*)&x_lo[row * LSTR_ + g * 8] = lo;
        const float* pw = wbase + row * (2 * D_) + g * 8;
        split8(*(const f32x4_t*)pw, *(const f32x4_t*)(pw + 4), hi, lo);
        *(short8*)&w_hi[row * LSTR_ + g * 8] = hi;
        *(short8*)&w_lo[row * LSTR_ + g * 8] = lo;
    }
    __syncthreads();

    const int rsel = lane & 15;
    const int gq   = lane >> 4;           // 0..3
    const int wm   = (wave & 1) * 32;     // wave's m offset in tile
    const int wh   = (wave >> 1) * 32;    // wave's h offset in tile

    f32x4_t acc[2][2] = {{{0.f,0.f,0.f,0.f},{0.f,0.f,0.f,0.f}},
                         {{0.f,0.f,0.f,0.f},{0.f,0.f,0.f,0.f}}};
    #pragma unroll
    for (int kk = 0; kk < KCH_; kk += 32) {
        const int goff = (kk >> 3) + gq;  // k-group for this lane
        short8 ahi[2], alo[2], bhi[2], blo[2];
        #pragma unroll
        for (int ms = 0; ms < 2; ++ms) {
            const int o = (wm + ms * 16 + rsel) * LSTR_ + goff * 8;
            ahi[ms] = *(const short8*)&x_hi[o];
            alo[ms] = *(const short8*)&x_lo[o];
        }
        #pragma unroll
        for (int hs = 0; hs < 2; ++hs) {
            const int o = (wh + hs * 16 + rsel) * LSTR_ + goff * 8;
            bhi[hs] = *(const short8*)&w_hi[o];
            blo[hs] = *(const short8*)&w_lo[o];
        }
        #pragma unroll
        for (int ms = 0; ms < 2; ++ms)
            #pragma unroll
            for (int hs = 0; hs < 2; ++hs) {
                acc[ms][hs] = __builtin_amdgcn_mfma_f32_16x16x32_bf16(ahi[ms], bhi[hs], acc[ms][hs], 0, 0, 0);
                acc[ms][hs] = __builtin_amdgcn_mfma_f32_16x16x32_bf16(ahi[ms], blo[hs], acc[ms][hs], 0, 0, 0);
                acc[ms][hs] = __builtin_amdgcn_mfma_f32_16x16x32_bf16(alo[ms], bhi[hs], acc[ms][hs], 0, 0, 0);
            }
    }

    // C/D layout: col(h)=lane&15, row(m)=(lane>>4)*4+reg  [m89/m91 HW-verified]
    float* dst = ws + (size_t)kc * CHF_ + (size_t)z * (M_ * HID_);
    const int mrow_base = mloc + wm + (lane >> 4) * 4;
    #pragma unroll
    for (int ms = 0; ms < 2; ++ms) {
        #pragma unroll
        for (int hs = 0; hs < 2; ++hs) {
            const int h = h0 + wh + hs * 16 + rsel;
            const float bias = (z == 0 && kc == 0) ? b1[h] : 0.f;
            #pragma unroll
            for (int r = 0; r < 4; ++r) {
                dst[(mrow_base + ms * 16 + r) * HID_ + h] = acc[ms][hs][r] + bias;
            }
        }
    }
}

// Stage 2: out[i,j,b,c] = relu(ha[i,b,:]+hb[j,b,:]) . W2[c,:] + b2[c]
// grid (6, 6, 16), block 256: one (i,j) per thread. W2/b2 scalar-loaded;
// inner loop packed-FP32 (v_pk_add/v_pk_fma), dual 2-wide accumulators.
__global__ __launch_bounds__(256) void stage2(
    const float* __restrict__ ws,
    const float* __restrict__ W2,
    const float* __restrict__ b2,
    float* __restrict__ out)
{
    __shared__ float ha_s[16 * 132];
    __shared__ float hb_s[16 * 132];

    const int t  = threadIdx.x;
    const int i0 = blockIdx.x * 16;
    const int j0 = blockIdx.y * 16;
    const int b  = blockIdx.z;

    {
        const int r = t >> 4;
        const int c = (t & 15) * 8;
        const float* pHa = ws + ((i0 + r) * B_ + b) * HID_ + c;               // kc=0, z=0
        const float* pHb = ws + (M_ * HID_) + ((j0 + r) * B_ + b) * HID_ + c; // kc=0, z=1
        f32x4_t a0 = *(const f32x4_t*)pHa,  a1  = *(const f32x4_t*)(pHa + 4);
        f32x4_t b0 = *(const f32x4_t*)pHb,  b1v = *(const f32x4_t*)(pHb + 4);
        #pragma unroll
        for (int kc = 1; kc < KC_; ++kc) {
            const float* qa = pHa + (size_t)kc * CHF_;
            const float* qb = pHb + (size_t)kc * CHF_;
            a0  += *(const f32x4_t*)qa;   a1  += *(const f32x4_t*)(qa + 4);
            b0  += *(const f32x4_t*)qb;   b1v += *(const f32x4_t*)(qb + 4);
        }
        *(f32x4_t*)&ha_s[r * 132 + c]     = a0;
        *(f32x4_t*)&ha_s[r * 132 + c + 4] = a1;
        *(f32x4_t*)&hb_s[r * 132 + c]     = b0;
        *(f32x4_t*)&hb_s[r * 132 + c + 4] = b1v;
    }
    __syncthreads();

    const int ti = t >> 4, tj = t & 15;
    const float* pa = &ha_s[ti * 132];
    const float* pb = &hb_s[tj * 132];
    f32x2_t acc0 = {0.f, 0.f}, acc1 = {0.f, 0.f};
    #pragma unroll
    for (int h = 0; h < HID_; h += 4) {
        f32x4_t av = *(const f32x4_t*)(pa + h);        // ds_read_b128
        f32x4_t bv = *(const f32x4_t*)(pb + h);        // ds_read_b128
        f32x4_t w0 = *(const f32x4_t*)(W2 + h);        // uniform -> s_load
        f32x4_t w1 = *(const f32x4_t*)(W2 + HID_ + h); // uniform -> s_load
        f32x2_t alo = {av[0], av[1]}, ahi = {av[2], av[3]};
        f32x2_t blo = {bv[0], bv[1]}, bhi = {bv[2], bv[3]};
        f32x2_t s0 = pk_add(alo, blo);
        f32x2_t s1 = pk_add(ahi, bhi);
        s0[0] = fmaxf(s0[0], 0.f); s0[1] = fmaxf(s0[1], 0.f);
        s1[0] = fmaxf(s1[0], 0.f); s1[1] = fmaxf(s1[1], 0.f);
        f32x2_t w0lo = {w0[0], w0[1]}, w0hi = {w0[2], w0[3]};
        f32x2_t w1lo = {w1[0], w1[1]}, w1hi = {w1[2], w1[3]};
        pk_fma(acc0, s0, w0lo); pk_fma(acc0, s1, w0hi);
        pk_fma(acc1, s0, w1lo); pk_fma(acc1, s1, w1hi);
    }

    const int i = i0 + ti, j = j0 + tj;
    const int idx = ((i * S_ + j) * B_ + b) * 2;
    f32x2_t o = { acc0[0] + acc0[1] + b2[0], acc1[0] + acc1[1] + b2[1] };
    *(f32x2_t*)(out + idx) = o;
}

// Fallback if ws is unusable: recompute ha/hb tiles per block. Correctness-only.
__global__ __launch_bounds__(256) void fused_fallback(
    const float* __restrict__ emb,
    const float* __restrict__ embc,
    const float* __restrict__ W1,
    const float* __restrict__ b1,
    const float* __restrict__ W2,
    const float* __restrict__ b2,
    float* __restrict__ out)
{
    __shared__ float ha_s[16 * 132];
    __shared__ float hb_s[16 * 132];

    const int t  = threadIdx.x;
    const int i0 = blockIdx.x * 16;
    const int j0 = blockIdx.y * 16;
    const int b  = blockIdx.z;

    for (int o = t; o < 4096; o += 256) {
        const int side = o >> 11;
        const int mi   = (o >> 7) & 15;
        const int h    = o & 127;
        const int srow = ((side ? j0 : i0) + mi) * B_ + b;
        const float* x = (side ? embc : emb) + srow * D_;
        const float* w = W1 + h * (2 * D_) + side * D_;
        float s = side ? 0.f : b1[h];
        for (int d = 0; d < D_; d += 4) {
            f32x4_t xv = *(const f32x4_t*)(x + d);
            f32x4_t wv = *(const f32x4_t*)(w + d);
            s = fmaf(xv[0], wv[0], s);
            s = fmaf(xv[1], wv[1], s);
            s = fmaf(xv[2], wv[2], s);
            s = fmaf(xv[3], wv[3], s);
        }
        (side ? hb_s : ha_s)[mi * 132 + h] = s;
    }
    __syncthreads();

    const int ti = t >> 4, tj = t & 15;
    const float* pa = &ha_s[ti * 132];
    const float* pb = &hb_s[tj * 132];
    float acc0 = 0.f, acc1 = 0.f;
    #pragma unroll
    for (int h = 0; h < HID_; h += 4) {
        f32x4_t av = *(const f32x4_t*)(pa + h);
        f32x4_t bv = *(const f32x4_t*)(pb + h);
        f32x4_t w0 = *(const f32x4_t*)(W2 + h);
        f32x4_t w1 = *(const f32x4_t*)(W2 + HID_ + h);
        #pragma unroll
        for (int q = 0; q < 4; ++q) {
            float v = fmaxf(av[q] + bv[q], 0.f);
            acc0 = fmaf(v, w0[q], acc0);
            acc1 = fmaf(v, w1[q], acc1);
        }
    }
    const int i = i0 + ti, j = j0 + tj;
    const int idx = ((i * S_ + j) * B_ + b) * 2;
    f32x2_t ov = { acc0 + b2[0], acc1 + b2[1] };
    *(f32x2_t*)(out + idx) = ov;
}

extern "C" void kernel_launch(void* const* d_in, const int* in_sizes, int n_in,
                              void* d_out, int out_size, void* d_ws, size_t ws_size,
                              hipStream_t stream) {
    const float* emb  = (const float*)d_in[0];
    // d_in[1] = umask (unused), d_in[2] = qmask (unused)
    const float* embc = (const float*)d_in[3];
    const float* W1   = (const float*)d_in[4];
    const float* b1   = (const float*)d_in[5];
    const float* W2   = (const float*)d_in[6];
    const float* b2   = (const float*)d_in[7];
    float* out = (float*)d_out;

    const size_t need = (size_t)KC_ * CHF_ * sizeof(float);  // 6.29 MB
    if (d_ws != nullptr && ws_size >= need) {
        float* ws = (float*)d_ws;   // ws[kc][z][m][h]
        stage1_mfma<<<dim3(48, 2, KC_), 256, 0, stream>>>(emb, embc, W1, b1, ws);
        stage2<<<dim3(6, 6, 16), 256, 0, stream>>>(ws, W2, b2, out);
    } else {
        fused_fallback<<<dim3(6, 6, 16), 256, 0, stream>>>(emb, embc, W1, b1, W2, b2, out);
    }
}

// Round 11
// 83.415 us; speedup vs baseline: 1.0397x; 1.0397x over previous
//
#include <hip/hip_runtime.h>

#define S_   96
#define B_   16
#define D_   512
#define HID_ 128
#define M_   (S_ * B_)     // 1536
#define KCH_ 128           // K staging chunk
#define LSTR_ 136          // LDS row stride in halfwords (272 B): uniform bank quads

// Own POD vector types only — no HIP vector classes (non-POD, poison unions).
typedef __attribute__((ext_vector_type(4))) float        f32x4_t;
typedef __attribute__((ext_vector_type(2))) float        f32x2_t;
typedef __attribute__((ext_vector_type(4))) unsigned int u32x4_t;
typedef __attribute__((ext_vector_type(8))) short        short8;   // bf16x8 MFMA frag

// Split 8 f32 into hi/lo truncated-bf16 fragments (3-MFMA f32-grade emulation).
static __device__ __forceinline__ void split8(f32x4_t a, f32x4_t b,
                                              short8& hi, short8& lo) {
    float f[8];
    #pragma unroll
    for (int j = 0; j < 4; ++j) { f[j] = a[j]; f[4 + j] = b[j]; }
    unsigned int hb[8], lb[8];
    #pragma unroll
    for (int j = 0; j < 8; ++j) {
        unsigned int u = __float_as_uint(f[j]);
        float hf = __uint_as_float(u & 0xffff0000u);
        hb[j] = u >> 16;
        lb[j] = __float_as_uint(f[j] - hf) >> 16;
    }
    union { u32x4_t u; short8 s; } H, L;
    #pragma unroll
    for (int j = 0; j < 4; ++j) {
        H.u[j] = hb[2 * j] | (hb[2 * j + 1] << 16);
        L.u[j] = lb[2 * j] | (lb[2 * j + 1] << 16);
    }
    hi = H.s; lo = L.s;
}

// Stage 1 (MFMA, canonical K-loop, pre-split hi/lo LDS tiles, FINAL write):
//   ws[z][m][h] = sum_d x[m][d]*W1[h][z*512+d] + (z==0 ? b1[h] : 0)
// grid (96 m-tiles x 4 h-quarters) = 384 blocks; block 256 = 4 waves (2x2),
// wave = one 16x16 C tile; accumulators persist across 4 K-chunks of 128.
__global__ __launch_bounds__(256) void stage1_mfma(
    const float* __restrict__ emb,
    const float* __restrict__ embc,
    const float* __restrict__ W1,
    const float* __restrict__ b1,
    float* __restrict__ ws)
{
    __shared__ short x_hi[32 * LSTR_];   // 8.7 KB each, 34.8 KB total
    __shared__ short x_lo[32 * LSTR_];
    __shared__ short w_hi[32 * LSTR_];
    __shared__ short w_lo[32 * LSTR_];

    const int t    = threadIdx.x;
    const int wave = t >> 6;
    const int lane = t & 63;
    const int bx   = blockIdx.x;          // m-tile (32 rows); z boundary at bx=48
    const int h0   = blockIdx.y * 32;     // h-quarter

    const int z    = (bx >= 48) ? 1 : 0;
    const int mloc = bx * 32 - z * M_;    // row start within emb/embc

    const float* xbase = (z ? embc : emb) + (size_t)mloc * D_;
    const float* wbase = W1 + (size_t)h0 * (2 * D_) + z * D_;

    const int rsel = lane & 15;
    const int gq   = lane >> 4;           // 0..3
    const int wm   = (wave & 1) * 16;     // wave m offset in tile
    const int wh   = (wave >> 1) * 16;    // wave h offset in tile

    f32x4_t acc = {0.f, 0.f, 0.f, 0.f};

    for (int kc = 0; kc < D_; kc += KCH_) {
        // Staging + one-time split: 512 k-groups each for x and w; 2+2 per thread.
        #pragma unroll
        for (int rep = 0; rep < 2; ++rep) {
            const int idx = rep * 256 + t;    // [0,512)
            const int row = idx >> 4;         // 0..31
            const int g   = idx & 15;         // k-group (8 floats)
            short8 hi, lo;
            const float* px = xbase + row * D_ + kc + g * 8;
            split8(*(const f32x4_t*)px, *(const f32x4_t*)(px + 4), hi, lo);
            *(short8*)&x_hi[row * LSTR_ + g * 8] = hi;
            *(short8*)&x_lo[row * LSTR_ + g * 8] = lo;
            const float* pw = wbase + row * (2 * D_) + kc + g * 8;
            split8(*(const f32x4_t*)pw, *(const f32x4_t*)(pw + 4), hi, lo);
            *(short8*)&w_hi[row * LSTR_ + g * 8] = hi;
            *(short8*)&w_lo[row * LSTR_ + g * 8] = lo;
        }
        __syncthreads();

        #pragma unroll
        for (int kk = 0; kk < KCH_; kk += 32) {
            const int goff = (kk >> 3) + gq;
            const int oa = (wm + rsel) * LSTR_ + goff * 8;
            const int ob = (wh + rsel) * LSTR_ + goff * 8;
            short8 ahi = *(const short8*)&x_hi[oa];
            short8 alo = *(const short8*)&x_lo[oa];
            short8 bhi = *(const short8*)&w_hi[ob];
            short8 blo = *(const short8*)&w_lo[ob];
            acc = __builtin_amdgcn_mfma_f32_16x16x32_bf16(ahi, bhi, acc, 0, 0, 0);
            acc = __builtin_amdgcn_mfma_f32_16x16x32_bf16(ahi, blo, acc, 0, 0, 0);
            acc = __builtin_amdgcn_mfma_f32_16x16x32_bf16(alo, bhi, acc, 0, 0, 0);
        }
        __syncthreads();   // protect LDS before next chunk's overwrite
    }

    // C/D layout: col(h)=lane&15, row(m)=(lane>>4)*4+reg  [m89/m91 HW-verified]
    const int h = h0 + wh + rsel;
    const float bias = z ? 0.f : b1[h];
    const int mrow = mloc + wm + (lane >> 4) * 4;
    float* dst = ws + (size_t)z * (M_ * HID_);
    #pragma unroll
    for (int r = 0; r < 4; ++r) {
        dst[(mrow + r) * HID_ + h] = acc[r] + bias;
    }
}

// Stage 2 (R9-winning form): out[i,j,b,c] = relu(ha[i,b,:]+hb[j,b,:]).W2[c,:]+b2[c]
// grid (6, 6, 16), block 256: one (i,j) per thread. W2/b2 scalar-loaded.
__global__ __launch_bounds__(256) void stage2(
    const float* __restrict__ ws,
    const float* __restrict__ W2,
    const float* __restrict__ b2,
    float* __restrict__ out)
{
    __shared__ float ha_s[16 * 132];
    __shared__ float hb_s[16 * 132];

    const int t  = threadIdx.x;
    const int i0 = blockIdx.x * 16;
    const int j0 = blockIdx.y * 16;
    const int b  = blockIdx.z;

    {
        const int r = t >> 4;
        const int c = (t & 15) * 8;
        const float* pHa = ws + ((i0 + r) * B_ + b) * HID_ + c;               // z=0
        const float* pHb = ws + (M_ * HID_) + ((j0 + r) * B_ + b) * HID_ + c; // z=1
        *(f32x4_t*)&ha_s[r * 132 + c]     = *(const f32x4_t*)pHa;
        *(f32x4_t*)&ha_s[r * 132 + c + 4] = *(const f32x4_t*)(pHa + 4);
        *(f32x4_t*)&hb_s[r * 132 + c]     = *(const f32x4_t*)pHb;
        *(f32x4_t*)&hb_s[r * 132 + c + 4] = *(const f32x4_t*)(pHb + 4);
    }
    __syncthreads();

    const int ti = t >> 4, tj = t & 15;
    const float* pa = &ha_s[ti * 132];
    const float* pb = &hb_s[tj * 132];
    float acc0 = 0.f, acc1 = 0.f;
    #pragma unroll
    for (int h = 0; h < HID_; h += 4) {
        f32x4_t av = *(const f32x4_t*)(pa + h);        // ds_read_b128
        f32x4_t bv = *(const f32x4_t*)(pb + h);        // ds_read_b128
        f32x4_t w0 = *(const f32x4_t*)(W2 + h);        // uniform -> s_load
        f32x4_t w1 = *(const f32x4_t*)(W2 + HID_ + h); // uniform -> s_load
        #pragma unroll
        for (int q = 0; q < 4; ++q) {
            float v = fmaxf(av[q] + bv[q], 0.f);
            acc0 = fmaf(v, w0[q], acc0);
            acc1 = fmaf(v, w1[q], acc1);
        }
    }

    const int i = i0 + ti, j = j0 + tj;
    const int idx = ((i * S_ + j) * B_ + b) * 2;
    f32x2_t o = { acc0 + b2[0], acc1 + b2[1] };
    *(f32x2_t*)(out + idx) = o;
}

// Fallback if ws is unusable: recompute ha/hb tiles per block. Correctness-only.
__global__ __launch_bounds__(256) void fused_fallback(
    const float* __restrict__ emb,
    const float* __restrict__ embc,
    const float* __restrict__ W1,
    const float* __restrict__ b1,
    const float* __restrict__ W2,
    const float* __restrict__ b2,
    float* __restrict__ out)
{
    __shared__ float ha_s[16 * 132];
    __shared__ float hb_s[16 * 132];

    const int t  = threadIdx.x;
    const int i0 = blockIdx.x * 16;
    const int j0 = blockIdx.y * 16;
    const int b  = blockIdx.z;

    for (int o = t; o < 4096; o += 256) {
        const int side = o >> 11;
        const int mi   = (o >> 7) & 15;
        const int h    = o & 127;
        const int srow = ((side ? j0 : i0) + mi) * B_ + b;
        const float* x = (side ? embc : emb) + srow * D_;
        const float* w = W1 + h * (2 * D_) + side * D_;
        float s = side ? 0.f : b1[h];
        for (int d = 0; d < D_; d += 4) {
            f32x4_t xv = *(const f32x4_t*)(x + d);
            f32x4_t wv = *(const f32x4_t*)(w + d);
            s = fmaf(xv[0], wv[0], s);
            s = fmaf(xv[1], wv[1], s);
            s = fmaf(xv[2], wv[2], s);
            s = fmaf(xv[3], wv[3], s);
        }
        (side ? hb_s : ha_s)[mi * 132 + h] = s;
    }
    __syncthreads();

    const int ti = t >> 4, tj = t & 15;
    const float* pa = &ha_s[ti * 132];
    const float* pb = &hb_s[tj * 132];
    float acc0 = 0.f, acc1 = 0.f;
    #pragma unroll
    for (int h = 0; h < HID_; h += 4) {
        f32x4_t av = *(const f32x4_t*)(pa + h);
        f32x4_t bv = *(const f32x4_t*)(pb + h);
        f32x4_t w0 = *(const f32x4_t*)(W2 + h);
        f32x4_t w1 = *(const f32x4_t*)(W2 + HID_ + h);
        #pragma unroll
        for (int q = 0; q < 4; ++q) {
            float v = fmaxf(av[q] + bv[q], 0.f);
            acc0 = fmaf(v, w0[q], acc0);
            acc1 = fmaf(v, w1[q], acc1);
        }
    }
    const int i = i0 + ti, j = j0 + tj;
    const int idx = ((i * S_ + j) * B_ + b) * 2;
    f32x2_t ov = { acc0 + b2[0], acc1 + b2[1] };
    *(f32x2_t*)(out + idx) = ov;
}

extern "C" void kernel_launch(void* const* d_in, const int* in_sizes, int n_in,
                              void* d_out, int out_size, void* d_ws, size_t ws_size,
                              hipStream_t stream) {
    const float* emb  = (const float*)d_in[0];
    // d_in[1] = umask (unused), d_in[2] = qmask (unused)
    const float* embc = (const float*)d_in[3];
    const float* W1   = (const float*)d_in[4];
    const float* b1   = (const float*)d_in[5];
    const float* W2   = (const float*)d_in[6];
    const float* b2   = (const float*)d_in[7];
    float* out = (float*)d_out;

    const size_t need = (size_t)2 * M_ * HID_ * sizeof(float);  // 1.57 MB
    if (d_ws != nullptr && ws_size >= need) {
        float* ws = (float*)d_ws;   // ws[z][m][h]
        stage1_mfma<<<dim3(96, 4), 256, 0, stream>>>(emb, embc, W1, b1, ws);
        stage2<<<dim3(6, 6, 16), 256, 0, stream>>>(ws, W2, b2, out);
    } else {
        fused_fallback<<<dim3(6, 6, 16), 256, 0, stream>>>(emb, embc, W1, b1, W2, b2, out);
    }
}

// Round 12
// 82.993 us; speedup vs baseline: 1.0450x; 1.0051x over previous
//
#include <hip/hip_runtime.h>

#define S_   96
#define B_   16
#define D_   512
#define HID_ 128
#define M_   (S_ * B_)     // 1536
#define KCH_ 128           // K staging chunk
#define LSTR_ 136          // LDS row stride in halfwords (272 B): uniform bank quads

// Own POD vector types only — no HIP vector classes (non-POD, poison unions).
typedef __attribute__((ext_vector_type(4))) float        f32x4_t;
typedef __attribute__((ext_vector_type(2))) float        f32x2_t;
typedef __attribute__((ext_vector_type(4))) unsigned int u32x4_t;
typedef __attribute__((ext_vector_type(8))) short        short8;   // bf16x8 MFMA frag

// Split 8 f32 into hi/lo truncated-bf16 fragments (3-MFMA f32-grade emulation).
static __device__ __forceinline__ void split8(f32x4_t a, f32x4_t b,
                                              short8& hi, short8& lo) {
    float f[8];
    #pragma unroll
    for (int j = 0; j < 4; ++j) { f[j] = a[j]; f[4 + j] = b[j]; }
    unsigned int hb[8], lb[8];
    #pragma unroll
    for (int j = 0; j < 8; ++j) {
        unsigned int u = __float_as_uint(f[j]);
        float hf = __uint_as_float(u & 0xffff0000u);
        hb[j] = u >> 16;
        lb[j] = __float_as_uint(f[j] - hf) >> 16;
    }
    union { u32x4_t u; short8 s; } H, L;
    #pragma unroll
    for (int j = 0; j < 4; ++j) {
        H.u[j] = hb[2 * j] | (hb[2 * j + 1] << 16);
        L.u[j] = lb[2 * j] | (lb[2 * j + 1] << 16);
    }
    hi = H.s; lo = L.s;
}

// Stage 1 (MFMA, canonical K-loop, pre-split hi/lo LDS tiles, FINAL write):
//   ws[z][m][h] = sum_d x[m][d]*W1[h][z*512+d] + (z==0 ? b1[h] : 0)
// grid (192 m-tiles x 4 h-quarters) = 768 blocks of 128 threads (2 waves)
// -> exactly 3 blocks/CU, no load-imbalance tail (vs 1.5 blocks/CU before).
// Block tile: 16m x 32h; wave = one 16x16 C tile; acc persists over 4 K-chunks.
__global__ __launch_bounds__(128) void stage1_mfma(
    const float* __restrict__ emb,
    const float* __restrict__ embc,
    const float* __restrict__ W1,
    const float* __restrict__ b1,
    float* __restrict__ ws)
{
    __shared__ short x_hi[16 * LSTR_];   // 4.35 KB
    __shared__ short x_lo[16 * LSTR_];
    __shared__ short w_hi[32 * LSTR_];   // 8.7 KB
    __shared__ short w_lo[32 * LSTR_];   // total 26.1 KB

    const int t    = threadIdx.x;        // 0..127
    const int wave = t >> 6;             // 0..1
    const int lane = t & 63;
    const int bx   = blockIdx.x;         // m-tile (16 rows); z boundary at bx=96
    const int h0   = blockIdx.y * 32;    // h-quarter (32 wide)

    const int z    = (bx >= 96) ? 1 : 0;
    const int mloc = bx * 16 - z * M_;   // row start within emb/embc

    const float* xbase = (z ? embc : emb) + (size_t)mloc * D_;
    const float* wbase = W1 + (size_t)h0 * (2 * D_) + z * D_;

    const int rsel = lane & 15;
    const int gq   = lane >> 4;          // 0..3
    const int wh   = wave * 16;          // wave h offset in tile

    f32x4_t acc = {0.f, 0.f, 0.f, 0.f};

    for (int kc = 0; kc < D_; kc += KCH_) {
        // Staging + one-time split. x: 256 k-groups (2/thread); w: 512 (4/thread).
        #pragma unroll
        for (int rep = 0; rep < 2; ++rep) {
            const int idx = rep * 128 + t;    // [0,256)
            const int row = idx >> 4;         // 0..15
            const int g   = idx & 15;         // k-group (8 floats)
            short8 hi, lo;
            const float* px = xbase + row * D_ + kc + g * 8;
            split8(*(const f32x4_t*)px, *(const f32x4_t*)(px + 4), hi, lo);
            *(short8*)&x_hi[row * LSTR_ + g * 8] = hi;
            *(short8*)&x_lo[row * LSTR_ + g * 8] = lo;
        }
        #pragma unroll
        for (int rep = 0; rep < 4; ++rep) {
            const int idx = rep * 128 + t;    // [0,512)
            const int row = idx >> 4;         // 0..31
            const int g   = idx & 15;
            short8 hi, lo;
            const float* pw = wbase + row * (2 * D_) + kc + g * 8;
            split8(*(const f32x4_t*)pw, *(const f32x4_t*)(pw + 4), hi, lo);
            *(short8*)&w_hi[row * LSTR_ + g * 8] = hi;
            *(short8*)&w_lo[row * LSTR_ + g * 8] = lo;
        }
        __syncthreads();

        #pragma unroll
        for (int kk = 0; kk < KCH_; kk += 32) {
            const int goff = (kk >> 3) + gq;
            const int oa = rsel * LSTR_ + goff * 8;
            const int ob = (wh + rsel) * LSTR_ + goff * 8;
            short8 ahi = *(const short8*)&x_hi[oa];
            short8 alo = *(const short8*)&x_lo[oa];
            short8 bhi = *(const short8*)&w_hi[ob];
            short8 blo = *(const short8*)&w_lo[ob];
            acc = __builtin_amdgcn_mfma_f32_16x16x32_bf16(ahi, bhi, acc, 0, 0, 0);
            acc = __builtin_amdgcn_mfma_f32_16x16x32_bf16(ahi, blo, acc, 0, 0, 0);
            acc = __builtin_amdgcn_mfma_f32_16x16x32_bf16(alo, bhi, acc, 0, 0, 0);
        }
        if (kc + KCH_ < D_) __syncthreads();   // protect LDS before next overwrite
    }

    // C/D layout: col(h)=lane&15, row(m)=(lane>>4)*4+reg  [m89/m91 HW-verified]
    const int h = h0 + wh + rsel;
    const float bias = z ? 0.f : b1[h];
    const int mrow = mloc + (lane >> 4) * 4;
    float* dst = ws + (size_t)z * (M_ * HID_);
    #pragma unroll
    for (int r = 0; r < 4; ++r) {
        dst[(mrow + r) * HID_ + h] = acc[r] + bias;
    }
}

// Stage 2 (R9-winning form): out[i,j,b,c] = relu(ha[i,b,:]+hb[j,b,:]).W2[c,:]+b2[c]
// grid (6, 6, 16), block 256: one (i,j) per thread. W2/b2 scalar-loaded.
__global__ __launch_bounds__(256) void stage2(
    const float* __restrict__ ws,
    const float* __restrict__ W2,
    const float* __restrict__ b2,
    float* __restrict__ out)
{
    __shared__ float ha_s[16 * 132];
    __shared__ float hb_s[16 * 132];

    const int t  = threadIdx.x;
    const int i0 = blockIdx.x * 16;
    const int j0 = blockIdx.y * 16;
    const int b  = blockIdx.z;

    {
        const int r = t >> 4;
        const int c = (t & 15) * 8;
        const float* pHa = ws + ((i0 + r) * B_ + b) * HID_ + c;               // z=0
        const float* pHb = ws + (M_ * HID_) + ((j0 + r) * B_ + b) * HID_ + c; // z=1
        *(f32x4_t*)&ha_s[r * 132 + c]     = *(const f32x4_t*)pHa;
        *(f32x4_t*)&ha_s[r * 132 + c + 4] = *(const f32x4_t*)(pHa + 4);
        *(f32x4_t*)&hb_s[r * 132 + c]     = *(const f32x4_t*)pHb;
        *(f32x4_t*)&hb_s[r * 132 + c + 4] = *(const f32x4_t*)(pHb + 4);
    }
    __syncthreads();

    const int ti = t >> 4, tj = t & 15;
    const float* pa = &ha_s[ti * 132];
    const float* pb = &hb_s[tj * 132];
    float acc0 = 0.f, acc1 = 0.f;
    #pragma unroll
    for (int h = 0; h < HID_; h += 4) {
        f32x4_t av = *(const f32x4_t*)(pa + h);        // ds_read_b128
        f32x4_t bv = *(const f32x4_t*)(pb + h);        // ds_read_b128
        f32x4_t w0 = *(const f32x4_t*)(W2 + h);        // uniform -> s_load
        f32x4_t w1 = *(const f32x4_t*)(W2 + HID_ + h); // uniform -> s_load
        #pragma unroll
        for (int q = 0; q < 4; ++q) {
            float v = fmaxf(av[q] + bv[q], 0.f);
            acc0 = fmaf(v, w0[q], acc0);
            acc1 = fmaf(v, w1[q], acc1);
        }
    }

    const int i = i0 + ti, j = j0 + tj;
    const int idx = ((i * S_ + j) * B_ + b) * 2;
    f32x2_t o = { acc0 + b2[0], acc1 + b2[1] };
    *(f32x2_t*)(out + idx) = o;
}

// Fallback if ws is unusable: recompute ha/hb tiles per block. Correctness-only.
__global__ __launch_bounds__(256) void fused_fallback(
    const float* __restrict__ emb,
    const float* __restrict__ embc,
    const float* __restrict__ W1,
    const float* __restrict__ b1,
    const float* __restrict__ W2,
    const float* __restrict__ b2,
    float* __restrict__ out)
{
    __shared__ float ha_s[16 * 132];
    __shared__ float hb_s[16 * 132];

    const int t  = threadIdx.x;
    const int i0 = blockIdx.x * 16;
    const int j0 = blockIdx.y * 16;
    const int b  = blockIdx.z;

    for (int o = t; o < 4096; o += 256) {
        const int side = o >> 11;
        const int mi   = (o >> 7) & 15;
        const int h    = o & 127;
        const int srow = ((side ? j0 : i0) + mi) * B_ + b;
        const float* x = (side ? embc : emb) + srow * D_;
        const float* w = W1 + h * (2 * D_) + side * D_;
        float s = side ? 0.f : b1[h];
        for (int d = 0; d < D_; d += 4) {
            f32x4_t xv = *(const f32x4_t*)(x + d);
            f32x4_t wv = *(const f32x4_t*)(w + d);
            s = fmaf(xv[0], wv[0], s);
            s = fmaf(xv[1], wv[1], s);
            s = fmaf(xv[2], wv[2], s);
            s = fmaf(xv[3], wv[3], s);
        }
        (side ? hb_s : ha_s)[mi * 132 + h] = s;
    }
    __syncthreads();

    const int ti = t >> 4, tj = t & 15;
    const float* pa = &ha_s[ti * 132];
    const float* pb = &hb_s[tj * 132];
    float acc0 = 0.f, acc1 = 0.f;
    #pragma unroll
    for (int h = 0; h < HID_; h += 4) {
        f32x4_t av = *(const f32x4_t*)(pa + h);
        f32x4_t bv = *(const f32x4_t*)(pb + h);
        f32x4_t w0 = *(const f32x4_t*)(W2 + h);
        f32x4_t w1 = *(const f32x4_t*)(W2 + HID_ + h);
        #pragma unroll
        for (int q = 0; q < 4; ++q) {
            float v = fmaxf(av[q] + bv[q], 0.f);
            acc0 = fmaf(v, w0[q], acc0);
            acc1 = fmaf(v, w1[q], acc1);
        }
    }
    const int i = i0 + ti, j = j0 + tj;
    const int idx = ((i * S_ + j) * B_ + b) * 2;
    f32x2_t ov = { acc0 + b2[0], acc1 + b2[1] };
    *(f32x2_t*)(out + idx) = ov;
}

extern "C" void kernel_launch(void* const* d_in, const int* in_sizes, int n_in,
                              void* d_out, int out_size, void* d_ws, size_t ws_size,
                              hipStream_t stream) {
    const float* emb  = (const float*)d_in[0];
    // d_in[1] = umask (unused), d_in[2] = qmask (unused)
    const float* embc = (const float*)d_in[3];
    const float* W1   = (const float*)d_in[4];
    const float* b1   = (const float*)d_in[5];
    const float* W2   = (const float*)d_in[6];
    const float* b2   = (const float*)d_in[7];
    float* out = (float*)d_out;

    const size_t need = (size_t)2 * M_ * HID_ * sizeof(float);  // 1.57 MB
    if (d_ws != nullptr && ws_size >= need) {
        float* ws = (float*)d_ws;   // ws[z][m][h]
        stage1_mfma<<<dim3(192, 4), 128, 0, stream>>>(emb, embc, W1, b1, ws);
        stage2<<<dim3(6, 6, 16), 256, 0, stream>>>(ws, W2, b2, out);
    } else {
        fused_fallback<<<dim3(6, 6, 16), 256, 0, stream>>>(emb, embc, W1, b1, W2, b2, out);
    }
}